// Round 1
// baseline (9056.559 us; speedup 1.0000x reference)
//
#include <hip/hip_runtime.h>
#include <math.h>

// Problem constants
constexpr int Bc  = 4;
constexpr int Tc  = 2048;
constexpr int Vc  = 2048;
constexpr int Dc  = 512;
constexpr int Hc  = 8;
constexpr int HDc = 64;
constexpr int Lc  = 4;

// ---------------------------------------------------------------------------
// Tiled fp32 GEMM, NT layout:  C[M,N] = scale * A[M,K] @ W[N,K]^T  (+ pos add)
// BM=BN=64, BK=32, 256 threads, 4x4 micro-tile per thread.
// pos != nullptr => C[m][n] += pos[(m % T)*D + n]  (only used for embed, N==D)
// ---------------------------------------------------------------------------
__global__ __launch_bounds__(256) void gemm_nt(
    const float* __restrict__ A, const float* __restrict__ W,
    float* __restrict__ C, const float* __restrict__ pos,
    int K, int N, float scale)
{
    __shared__ float As[64][33];
    __shared__ float Bs[64][33];

    const int tid = threadIdx.x;
    const int m0  = blockIdx.y * 64;
    const int n0  = blockIdx.x * 64;
    const int lr  = tid >> 2;           // 0..63 : row within tile for loads
    const int lk0 = (tid & 3) << 3;     // 0,8,16,24 : k offset (2 float4 each)
    const int tx  = tid & 15;
    const int ty  = tid >> 4;

    float acc[4][4];
#pragma unroll
    for (int i = 0; i < 4; ++i)
#pragma unroll
        for (int j = 0; j < 4; ++j) acc[i][j] = 0.f;

    const float* Arow = A + (size_t)(m0 + lr) * K;
    const float* Wrow = W + (size_t)(n0 + lr) * K;

    for (int kt = 0; kt < K; kt += 32) {
        float4 a0 = *(const float4*)(Arow + kt + lk0);
        float4 a1 = *(const float4*)(Arow + kt + lk0 + 4);
        float4 b0 = *(const float4*)(Wrow + kt + lk0);
        float4 b1 = *(const float4*)(Wrow + kt + lk0 + 4);

        As[lr][lk0 + 0] = a0.x; As[lr][lk0 + 1] = a0.y;
        As[lr][lk0 + 2] = a0.z; As[lr][lk0 + 3] = a0.w;
        As[lr][lk0 + 4] = a1.x; As[lr][lk0 + 5] = a1.y;
        As[lr][lk0 + 6] = a1.z; As[lr][lk0 + 7] = a1.w;
        Bs[lr][lk0 + 0] = b0.x; Bs[lr][lk0 + 1] = b0.y;
        Bs[lr][lk0 + 2] = b0.z; Bs[lr][lk0 + 3] = b0.w;
        Bs[lr][lk0 + 4] = b1.x; Bs[lr][lk0 + 5] = b1.y;
        Bs[lr][lk0 + 6] = b1.z; Bs[lr][lk0 + 7] = b1.w;

        __syncthreads();

#pragma unroll
        for (int kk = 0; kk < 32; ++kk) {
            float av[4], bv[4];
#pragma unroll
            for (int i = 0; i < 4; ++i) av[i] = As[ty * 4 + i][kk];
#pragma unroll
            for (int j = 0; j < 4; ++j) bv[j] = Bs[tx * 4 + j][kk];
#pragma unroll
            for (int i = 0; i < 4; ++i)
#pragma unroll
                for (int j = 0; j < 4; ++j)
                    acc[i][j] = fmaf(av[i], bv[j], acc[i][j]);
        }
        __syncthreads();
    }

#pragma unroll
    for (int i = 0; i < 4; ++i) {
        const int m = m0 + ty * 4 + i;
#pragma unroll
        for (int j = 0; j < 4; ++j) {
            const int n = n0 + tx * 4 + j;
            float r = acc[i][j] * scale;
            if (pos) r += pos[(size_t)(m & (Tc - 1)) * Dc + n];
            C[(size_t)m * N + n] = r;
        }
    }
}

// ---------------------------------------------------------------------------
// Flash attention, fp32. One lane == one q row (q and O accumulator in regs).
// K/V rows read with wave-uniform addresses -> scalar loads (SMEM pipe).
// grid = B*H*(T/64) blocks of 64 threads.
// q,k,v,o layouts: [B, T, D] with head h occupying cols h*HD .. h*HD+63.
// ---------------------------------------------------------------------------
__global__ __launch_bounds__(64) void attn_k(
    const float* __restrict__ q, const float* __restrict__ k,
    const float* __restrict__ v, float* __restrict__ o)
{
    const int bid  = blockIdx.x;
    const int qt   = bid & 31;         // T/64 = 32 q-tiles
    const int bh   = bid >> 5;
    const int hh   = bh & (Hc - 1);
    const int bb   = bh >> 3;
    const int lane = threadIdx.x;
    const int t    = qt * 64 + lane;

    const float* qp = q + ((size_t)(bb * Tc + t) * Dc + hh * HDc);
    float4 qv[16];
#pragma unroll
    for (int i = 0; i < 16; ++i) qv[i] = *(const float4*)(qp + i * 4);

    const float* kb = k + ((size_t)bb * Tc * Dc + hh * HDc);
    const float* vb = v + ((size_t)bb * Tc * Dc + hh * HDc);

    float4 ov[16];
#pragma unroll
    for (int i = 0; i < 16; ++i) ov[i] = make_float4(0.f, 0.f, 0.f, 0.f);
    float mrun = -1e30f, lrun = 0.f;

    for (int kj = 0; kj < Tc; kj += 8) {
        float s[8];
#pragma unroll
        for (int j = 0; j < 8; ++j) {
            const float* kr = kb + (size_t)(kj + j) * Dc;
            float ax = 0.f, ay = 0.f, az = 0.f, aw = 0.f;
#pragma unroll
            for (int i = 0; i < 16; ++i) {
                float4 kv = *(const float4*)(kr + i * 4);
                ax = fmaf(qv[i].x, kv.x, ax);
                ay = fmaf(qv[i].y, kv.y, ay);
                az = fmaf(qv[i].z, kv.z, az);
                aw = fmaf(qv[i].w, kv.w, aw);
            }
            s[j] = ((ax + ay) + (az + aw)) * 0.125f;  // * HD^-1/2
        }

        float mt = s[0];
#pragma unroll
        for (int j = 1; j < 8; ++j) mt = fmaxf(mt, s[j]);
        const float mnew = fmaxf(mrun, mt);
        const float f    = __expf(mrun - mnew);

        float p[8];
        float ps = 0.f;
#pragma unroll
        for (int j = 0; j < 8; ++j) { p[j] = __expf(s[j] - mnew); ps += p[j]; }
        lrun = lrun * f + ps;

#pragma unroll
        for (int i = 0; i < 16; ++i) {
            ov[i].x *= f; ov[i].y *= f; ov[i].z *= f; ov[i].w *= f;
        }
#pragma unroll
        for (int j = 0; j < 8; ++j) {
            const float* vr = vb + (size_t)(kj + j) * Dc;
#pragma unroll
            for (int i = 0; i < 16; ++i) {
                float4 vv = *(const float4*)(vr + i * 4);
                ov[i].x = fmaf(p[j], vv.x, ov[i].x);
                ov[i].y = fmaf(p[j], vv.y, ov[i].y);
                ov[i].z = fmaf(p[j], vv.z, ov[i].z);
                ov[i].w = fmaf(p[j], vv.w, ov[i].w);
            }
        }
        mrun = mnew;
    }

    const float inv = 1.f / lrun;
    float* op = o + ((size_t)(bb * Tc + t) * Dc + hh * HDc);
#pragma unroll
    for (int i = 0; i < 16; ++i) {
        float4 r = make_float4(ov[i].x * inv, ov[i].y * inv,
                               ov[i].z * inv, ov[i].w * inv);
        *(float4*)(op + i * 4) = r;
    }
}

// ---------------------------------------------------------------------------
// logits[b][v] = scale * sum_d h[b, T-1, d] * readout[v][d]
// 8192 outputs, one per thread.
// ---------------------------------------------------------------------------
__global__ __launch_bounds__(256) void readout_k(
    const float* __restrict__ h, const float* __restrict__ ro,
    float* __restrict__ out, float scale)
{
    const int idx = blockIdx.x * 256 + threadIdx.x;   // 0..8191
    const int vv  = idx & (Vc - 1);
    const int bb  = idx >> 11;
    const float* hp = h + (size_t)(bb * Tc + (Tc - 1)) * Dc;
    const float* rp = ro + (size_t)vv * Dc;
    float ax = 0.f, ay = 0.f, az = 0.f, aw = 0.f;
#pragma unroll 8
    for (int i = 0; i < Dc / 4; ++i) {
        float4 hv = *(const float4*)(hp + i * 4);
        float4 rv = *(const float4*)(rp + i * 4);
        ax = fmaf(hv.x, rv.x, ax);
        ay = fmaf(hv.y, rv.y, ay);
        az = fmaf(hv.z, rv.z, az);
        aw = fmaf(hv.w, rv.w, aw);
    }
    out[idx] = ((ax + ay) + (az + aw)) * scale;
}

// ---------------------------------------------------------------------------
extern "C" void kernel_launch(void* const* d_in, const int* in_sizes, int n_in,
                              void* d_out, int out_size, void* d_ws, size_t ws_size,
                              hipStream_t stream)
{
    const float* x    = (const float*)d_in[0];
    const float* temb = (const float*)d_in[1];
    const float* pemb = (const float*)d_in[2];
    const float* Wk   = (const float*)d_in[3];
    const float* Wq   = (const float*)d_in[4];
    const float* Wv   = (const float*)d_in[5];
    const float* Wp   = (const float*)d_in[6];
    const float* ro   = (const float*)d_in[7];
    float* out = (float*)d_out;

    const size_t SZ = (size_t)Bc * Tc * Dc;   // 4,194,304 floats per buffer
    float* ws = (float*)d_ws;
    float* hcur = ws;
    float* qb   = ws + SZ;
    float* kbuf = ws + 2 * SZ;
    float* vbuf = ws + 3 * SZ;

    const float s_emb  = 1.0f / sqrtf((float)Vc);
    const float s_proj = 1.0f / sqrtf((float)Dc);

    const dim3 gemmGrid(Dc / 64, (Bc * Tc) / 64);   // (8, 128)

    // h = x @ temb^T * s_emb + pos
    gemm_nt<<<gemmGrid, 256, 0, stream>>>(x, temb, hcur, pemb, Vc, Dc, s_emb);

    for (int l = 0; l < Lc; ++l) {
        const float* wq = Wq + (size_t)l * Dc * Dc;
        const float* wk = Wk + (size_t)l * Dc * Dc;
        const float* wv = Wv + (size_t)l * Dc * Dc;
        const float* wp = Wp + (size_t)l * Dc * Dc;

        gemm_nt<<<gemmGrid, 256, 0, stream>>>(hcur, wq, qb,   nullptr, Dc, Dc, s_proj);
        gemm_nt<<<gemmGrid, 256, 0, stream>>>(hcur, wk, kbuf, nullptr, Dc, Dc, s_proj);
        gemm_nt<<<gemmGrid, 256, 0, stream>>>(hcur, wv, vbuf, nullptr, Dc, Dc, s_proj);

        // attention output overwrites hcur (hcur is dead after q/k/v projections)
        attn_k<<<Bc * Hc * (Tc / 64), 64, 0, stream>>>(qb, kbuf, vbuf, hcur);

        // out-projection writes into qb (dead), then swap roles
        gemm_nt<<<gemmGrid, 256, 0, stream>>>(hcur, wp, qb, nullptr, Dc, Dc, s_proj);
        float* tmp = hcur; hcur = qb; qb = tmp;
    }

    readout_k<<<(Bc * Vc) / 256, 256, 0, stream>>>(hcur, ro, out, s_proj);
}

// Round 2
// 1666.854 us; speedup vs baseline: 5.4333x; 5.4333x over previous
//
#include <hip/hip_runtime.h>
#include <math.h>

typedef __attribute__((ext_vector_type(4))) float    f32x4;
typedef __attribute__((ext_vector_type(4))) _Float16 f16x4;
typedef __attribute__((ext_vector_type(8))) _Float16 f16x8;

constexpr int Bc  = 4;
constexpr int Tc  = 2048;
constexpr int Vc  = 2048;
constexpr int Dc  = 512;
constexpr int Hc  = 8;
constexpr int HDc = 64;
constexpr int Lc  = 4;

// ---------------------------------------------------------------------------
// f16-MFMA GEMM, NT layout: C[M,N] = scale * A[M,K] @ W[N,K]^T (+ pos add)
// fp32 in/out, f16 MFMA compute, fp32 accumulate.
// BM=BN=128, BK=32, 256 threads = 4 waves (2x2), each wave 64x64 out.
// ---------------------------------------------------------------------------
__global__ __launch_bounds__(256) void gemm_nt_f16(
    const float* __restrict__ A, const float* __restrict__ W,
    float* __restrict__ C, const float* __restrict__ pos,
    int K, int N, float scale)
{
    __shared__ _Float16 As[128][40];   // pad 40 halfs = 80B stride (16B-aligned frags)
    __shared__ _Float16 Bs[128][40];

    const int tid = threadIdx.x;
    const int w   = tid >> 6, l = tid & 63;
    const int li  = l & 15, lg = l >> 4;
    const int wm  = w >> 1, wn = w & 1;
    const int m0  = blockIdx.y * 128, n0 = blockIdx.x * 128;

    f32x4 acc[4][4];
#pragma unroll
    for (int i = 0; i < 4; ++i)
#pragma unroll
        for (int j = 0; j < 4; ++j) acc[i][j] = (f32x4){0.f, 0.f, 0.f, 0.f};

    for (int kt = 0; kt < K; kt += 32) {
#pragma unroll
        for (int i = 0; i < 4; ++i) {
            const int g   = i * 256 + tid;      // 0..1023 float4-slots
            const int row = g >> 3;             // 0..127
            const int c4  = (g & 7) * 4;        // 0,4,..,28
            float4 av = *(const float4*)(A + (size_t)(m0 + row) * K + kt + c4);
            float4 wv = *(const float4*)(W + (size_t)(n0 + row) * K + kt + c4);
            f16x4 ah = {(_Float16)av.x, (_Float16)av.y, (_Float16)av.z, (_Float16)av.w};
            f16x4 wh = {(_Float16)wv.x, (_Float16)wv.y, (_Float16)wv.z, (_Float16)wv.w};
            *(f16x4*)&As[row][c4] = ah;
            *(f16x4*)&Bs[row][c4] = wh;
        }
        __syncthreads();

        f16x8 af[4], bf[4];
#pragma unroll
        for (int mb = 0; mb < 4; ++mb)
            af[mb] = *(const f16x8*)&As[wm * 64 + mb * 16 + li][lg * 8];
#pragma unroll
        for (int nb = 0; nb < 4; ++nb)
            bf[nb] = *(const f16x8*)&Bs[wn * 64 + nb * 16 + li][lg * 8];

#pragma unroll
        for (int mb = 0; mb < 4; ++mb)
#pragma unroll
            for (int nb = 0; nb < 4; ++nb)
                acc[mb][nb] = __builtin_amdgcn_mfma_f32_16x16x32_f16(
                    af[mb], bf[nb], acc[mb][nb], 0, 0, 0);
        __syncthreads();
    }

    // Epilogue. C/D layout: col = lane&15, row = (lane>>4)*4 + reg.
#pragma unroll
    for (int mb = 0; mb < 4; ++mb) {
#pragma unroll
        for (int nb = 0; nb < 4; ++nb) {
            const int mbase = m0 + wm * 64 + mb * 16 + lg * 4;
            const int ncol  = n0 + wn * 64 + nb * 16 + li;
#pragma unroll
            for (int r = 0; r < 4; ++r) {
                const int m = mbase + r;
                float val = acc[mb][nb][r] * scale;
                if (pos) val += pos[(size_t)(m & (Tc - 1)) * Dc + ncol];
                C[(size_t)m * N + ncol] = val;
            }
        }
    }
}

// ---------------------------------------------------------------------------
// MFMA flash attention (f16 compute, fp32 accum/state).
// Swapped QK^T: S^T = mfma(A=K_tile, B=Q) so each lane holds
// P^T[k=(l>>4)*4+r][q=l&15] == the B-operand layout of the PV mfma.
// Block = 256 threads = 4 waves; each wave one 16-row q-tile; grid B*H*T/64.
// ---------------------------------------------------------------------------
__global__ __launch_bounds__(256) void attn_mfma(
    const float* __restrict__ q, const float* __restrict__ k,
    const float* __restrict__ v, float* __restrict__ o)
{
    const int bid = blockIdx.x;
    const int qt  = bid & 31;            // 32 blocks of 64 q-rows per (b,h)
    const int bh  = bid >> 5;
    const int hh  = bh & (Hc - 1);
    const int bb  = bh >> 3;
    const int w   = threadIdx.x >> 6;
    const int l   = threadIdx.x & 63;
    const int li  = l & 15, lg = l >> 4;
    const int q0  = qt * 64 + w * 16;

    // Q fragments (B-operand): lane holds Q[q0+li][hd0 + db*16 + lg*4 + j]
    const float* qp = q + ((size_t)(bb * Tc + q0 + li) * Dc + hh * HDc + lg * 4);
    f16x4 qf[4];
#pragma unroll
    for (int db = 0; db < 4; ++db) {
        float4 t = *(const float4*)(qp + db * 16);
        qf[db] = (f16x4){(_Float16)t.x, (_Float16)t.y, (_Float16)t.z, (_Float16)t.w};
    }

    const float* kb = k + (size_t)bb * Tc * Dc + hh * HDc;
    const float* vb = v + (size_t)bb * Tc * Dc + hh * HDc;

    f32x4 oacc[4];
#pragma unroll
    for (int db = 0; db < 4; ++db) oacc[db] = (f32x4){0.f, 0.f, 0.f, 0.f};
    float mrun = -1e30f, lrun = 0.f;

    for (int kt = 0; kt < Tc / 16; ++kt) {
        // ---- S^T = K_tile · Q^T  (A = K rows, contiguous float4 per lane)
        const float* kr = kb + (size_t)(kt * 16 + li) * Dc + lg * 4;
        f32x4 s = (f32x4){0.f, 0.f, 0.f, 0.f};
#pragma unroll
        for (int db = 0; db < 4; ++db) {
            float4 t = *(const float4*)(kr + db * 16);
            f16x4 kf = {(_Float16)t.x, (_Float16)t.y, (_Float16)t.z, (_Float16)t.w};
            s = __builtin_amdgcn_mfma_f32_16x16x16f16(kf, qf[db], s, 0, 0, 0);
        }
        const float s0 = s[0] * 0.125f, s1 = s[1] * 0.125f;
        const float s2 = s[2] * 0.125f, s3 = s[3] * 0.125f;

        // ---- online softmax over the 16 k's of this tile (4 regs x 4 lane-groups)
        float mt = fmaxf(fmaxf(s0, s1), fmaxf(s2, s3));
        mt = fmaxf(mt, __shfl_xor(mt, 16));
        mt = fmaxf(mt, __shfl_xor(mt, 32));
        const float mnew = fmaxf(mrun, mt);
        const float fsc  = __expf(mrun - mnew);
        const float p0 = __expf(s0 - mnew), p1 = __expf(s1 - mnew);
        const float p2 = __expf(s2 - mnew), p3 = __expf(s3 - mnew);
        float ps = (p0 + p1) + (p2 + p3);
        ps += __shfl_xor(ps, 16);
        ps += __shfl_xor(ps, 32);
        lrun = lrun * fsc + ps;

        f16x4 pf = {(_Float16)p0, (_Float16)p1, (_Float16)p2, (_Float16)p3};

        // ---- O^T += V^T · P^T   (A = V^T gather, B = pf already in-layout)
        const float* vr = vb + (size_t)(kt * 16 + lg * 4) * Dc + li;
#pragma unroll
        for (int db = 0; db < 4; ++db) oacc[db] *= fsc;
#pragma unroll
        for (int db = 0; db < 4; ++db) {
            f16x4 vf = {(_Float16)vr[0 * Dc + db * 16], (_Float16)vr[1 * Dc + db * 16],
                        (_Float16)vr[2 * Dc + db * 16], (_Float16)vr[3 * Dc + db * 16]};
            oacc[db] = __builtin_amdgcn_mfma_f32_16x16x16f16(vf, pf, oacc[db], 0, 0, 0);
        }
        mrun = mnew;
    }

    // ---- write O: lane holds q = li, d = db*16 + lg*4 + r
    const float inv = 1.f / lrun;
    float* op = o + ((size_t)(bb * Tc + q0 + li) * Dc + hh * HDc + lg * 4);
#pragma unroll
    for (int db = 0; db < 4; ++db) {
        f32x4 r = oacc[db] * inv;
        *(f32x4*)(op + db * 16) = r;
    }
}

// ---------------------------------------------------------------------------
// logits[b][v] = scale * sum_d h[b, T-1, d] * readout[v][d]
// ---------------------------------------------------------------------------
__global__ __launch_bounds__(256) void readout_k(
    const float* __restrict__ h, const float* __restrict__ ro,
    float* __restrict__ out, float scale)
{
    const int idx = blockIdx.x * 256 + threadIdx.x;   // 0..8191
    const int vv  = idx & (Vc - 1);
    const int bb  = idx >> 11;
    const float* hp = h + (size_t)(bb * Tc + (Tc - 1)) * Dc;
    const float* rp = ro + (size_t)vv * Dc;
    float ax = 0.f, ay = 0.f, az = 0.f, aw = 0.f;
#pragma unroll 8
    for (int i = 0; i < Dc / 4; ++i) {
        float4 hv = *(const float4*)(hp + i * 4);
        float4 rv = *(const float4*)(rp + i * 4);
        ax = fmaf(hv.x, rv.x, ax);
        ay = fmaf(hv.y, rv.y, ay);
        az = fmaf(hv.z, rv.z, az);
        aw = fmaf(hv.w, rv.w, aw);
    }
    out[idx] = ((ax + ay) + (az + aw)) * scale;
}

// ---------------------------------------------------------------------------
extern "C" void kernel_launch(void* const* d_in, const int* in_sizes, int n_in,
                              void* d_out, int out_size, void* d_ws, size_t ws_size,
                              hipStream_t stream)
{
    const float* x    = (const float*)d_in[0];
    const float* temb = (const float*)d_in[1];
    const float* pemb = (const float*)d_in[2];
    const float* Wk   = (const float*)d_in[3];
    const float* Wq   = (const float*)d_in[4];
    const float* Wv   = (const float*)d_in[5];
    const float* Wp   = (const float*)d_in[6];
    const float* ro   = (const float*)d_in[7];
    float* out = (float*)d_out;

    const size_t SZ = (size_t)Bc * Tc * Dc;   // floats per activation buffer
    float* ws = (float*)d_ws;
    float* hcur = ws;
    float* qb   = ws + SZ;
    float* kbuf = ws + 2 * SZ;
    float* vbuf = ws + 3 * SZ;

    const float s_emb  = 1.0f / sqrtf((float)Vc);
    const float s_proj = 1.0f / sqrtf((float)Dc);

    const dim3 gemmGrid(Dc / 128, (Bc * Tc) / 128);   // (4, 64)

    // h = x @ temb^T * s_emb + pos
    gemm_nt_f16<<<gemmGrid, 256, 0, stream>>>(x, temb, hcur, pemb, Vc, Dc, s_emb);

    for (int lyr = 0; lyr < Lc; ++lyr) {
        const float* wq = Wq + (size_t)lyr * Dc * Dc;
        const float* wk = Wk + (size_t)lyr * Dc * Dc;
        const float* wv = Wv + (size_t)lyr * Dc * Dc;
        const float* wp = Wp + (size_t)lyr * Dc * Dc;

        gemm_nt_f16<<<gemmGrid, 256, 0, stream>>>(hcur, wq, qb,   nullptr, Dc, Dc, s_proj);
        gemm_nt_f16<<<gemmGrid, 256, 0, stream>>>(hcur, wk, kbuf, nullptr, Dc, Dc, s_proj);
        gemm_nt_f16<<<gemmGrid, 256, 0, stream>>>(hcur, wv, vbuf, nullptr, Dc, Dc, s_proj);

        attn_mfma<<<Bc * Hc * (Tc / 64), 256, 0, stream>>>(qb, kbuf, vbuf, hcur);

        gemm_nt_f16<<<gemmGrid, 256, 0, stream>>>(hcur, wp, qb, nullptr, Dc, Dc, s_proj);
        float* tmp = hcur; hcur = qb; qb = tmp;
    }

    readout_k<<<(Bc * Vc) / 256, 256, 0, stream>>>(hcur, ro, out, s_proj);
}